// Round 11
// baseline (201.632 us; speedup 1.0000x reference)
//
#include <hip/hip_runtime.h>
#include <math.h>

#define B_ 4
#define N_ 20000
#define M_ 1024
#define K_ 16384
#define D_ 768

typedef __attribute__((ext_vector_type(8))) short bf16x8;
typedef __attribute__((ext_vector_type(4))) float f32x4;

// Workspace layout (ws is 768 MiB)
#define OFF_PART   0ul          // f32 [4][16][3]
#define OFF_RAD    1024ul       // f32 [4][16]
#define OFF_IDX    4096ul       // int [4][1024]
#define OFF_P4     32768ul      // float4 [4][16384] (1 MB)
#define OFF_NNP    1179648ul    // float2 [4][1024][4]
#define OFF_STATS  2097152ul    // float2 [4][16384] (512 KB)
#define OFF_AT     4194304ul    // bf16 [4][16384][256] (33.5 MB)
#define OFF_FUSED  41943040ul   // bf16 [4096][512] (4 MB)
#define OFF_H2     46137344ul   // bf16 [4096][256] (2 MB)
#define OFF_WGB    50331648ul   // bf16 [256][768]  (pw1*gamma)
#define OFF_WCAT   51380224ul   // bf16 [256][512]
#define OFF_WB4    52428800ul   // bf16 [256][256]
#define OFF_BC     53477376ul   // f32 [256]
#define OFF_S1     53481472ul   // f32 [256]
#define OFF_BS2    53485568ul   // f32 [256]

__device__ inline unsigned short f2bf(float x) {
    union { float f; unsigned int u; } v; v.f = x;
    unsigned int r = v.u + 0x7fffu + ((v.u >> 16) & 1u);
    return (unsigned short)(r >> 16);
}

__device__ inline float bf2f(unsigned short s) {
    union { unsigned int u; float f; } v; v.u = ((unsigned int)s) << 16;
    return v.f;
}

__device__ inline void gload_lds16(const void* g, void* lds) {
    __builtin_amdgcn_global_load_lds(
        (const __attribute__((address_space(1))) unsigned int*)g,
        (__attribute__((address_space(3))) unsigned int*)lds, 16, 0, 0);
}

__device__ inline void reduce_center(const float* part, int b,
                                     float& cx, float& cy, float& cz)
{
    cx = 0.f; cy = 0.f; cz = 0.f;
    #pragma unroll
    for (int r = 0; r < 16; ++r) {
        cx += part[(b*16+r)*3+0];
        cy += part[(b*16+r)*3+1];
        cz += part[(b*16+r)*3+2];
    }
    cx *= (1.f/N_); cy *= (1.f/N_); cz *= (1.f/N_);
}

__device__ inline float reduce_scale(const float* rad, int b)
{
    float m = 0.f;
    #pragma unroll
    for (int r = 0; r < 16; ++r) m = fmaxf(m, rad[b*16+r]);
    return fmaxf(sqrtf(m), 1e-6f);
}

// ---------------------------------------------------------------------------
// k_pre: wgb=bf16(pw1*gamma) (bid<768) + {Wcat-fold, bc, s1, bs2} (bid<256)
//        + cs_sum partials (bid>=768)
__global__ __launch_bounds__(256) void k_pre(
    const float* __restrict__ pc,
    const float* __restrict__ pw1, const float* __restrict__ pw2,
    const float* __restrict__ pb1, const float* __restrict__ pb2,
    const float* __restrict__ fw1, const float* __restrict__ fb1,
    const float* __restrict__ fw2,
    const float* __restrict__ ln_g, const float* __restrict__ ln_b,
    unsigned short* __restrict__ wgb, unsigned short* __restrict__ Wcat,
    unsigned short* __restrict__ Wb4, float* __restrict__ bc,
    float* __restrict__ s1, float* __restrict__ bs2,
    float* __restrict__ part)
{
    int bid = blockIdx.x, t = threadIdx.x;
    int lane = t & 63, wv = t >> 6;
    __shared__ float red[3][4];

    if (bid < 768) {
        int i0 = bid*256 + t;
        int c = i0 % 768;
        wgb[i0] = f2bf(pw1[i0] * ln_g[c]);
        if (i0 < 65536) {
            int o = i0 >> 8, cc = i0 & 255;
            Wcat[(size_t)o*512 + cc] = f2bf(fw1[(size_t)o*512 + cc]);
            Wb4[i0] = f2bf(fw2[i0]);
        }
    }
    if (bid < 256) {
        // Wcat[:,256:512] = bf16(fw1b @ pw2); bc = fw1b@pb2 + fb1 (o=bid)
        const float* fb = fw1 + (size_t)bid*512 + 256;
        float acc = 0.f;
        for (int j = 0; j < 256; ++j)
            acc = fmaf(fb[j], pw2[j*256 + t], acc);
        Wcat[(size_t)bid*512 + 256 + t] = f2bf(acc);
        float v = fb[t] * pb2[t];
        // s1[o] = sum_c pw1[o][c]*gamma[c];  bs2[o] = sum_c pw1[o][c]*beta[c] + pb1[o]
        const float* po = pw1 + (size_t)bid*768;
        float p1 = 0.f, p2 = 0.f;
        #pragma unroll
        for (int r = 0; r < 3; ++r) {
            int c = r*256 + t;
            float w = po[c];
            p1 = fmaf(w, ln_g[c], p1);
            p2 = fmaf(w, ln_b[c], p2);
        }
        for (int off = 32; off; off >>= 1) {
            v  += __shfl_down(v, off, 64);
            p1 += __shfl_down(p1, off, 64);
            p2 += __shfl_down(p2, off, 64);
        }
        if (!lane) { red[0][wv] = v; red[1][wv] = p1; red[2][wv] = p2; }
        __syncthreads();
        if (!t) {
            bc[bid]  = red[0][0]+red[0][1]+red[0][2]+red[0][3] + fb1[bid];
            s1[bid]  = red[1][0]+red[1][1]+red[1][2]+red[1][3];
            bs2[bid] = red[2][0]+red[2][1]+red[2][2]+red[2][3] + pb1[bid];
        }
    } else if (bid >= 768) {
        int pi = bid - 768;
        int b = pi >> 4, chunk = pi & 15;
        const float* p = pc + (size_t)b * N_ * 3;
        int i0 = chunk * 1250;
        float sx = 0.f, sy = 0.f, sz = 0.f;
        for (int i = i0 + t; i < i0 + 1250; i += 256) {
            sx += p[i*3+0]; sy += p[i*3+1]; sz += p[i*3+2];
        }
        for (int off = 32; off; off >>= 1) {
            sx += __shfl_down(sx, off, 64);
            sy += __shfl_down(sy, off, 64);
            sz += __shfl_down(sz, off, 64);
        }
        if (!lane) { red[0][wv] = sx; red[1][wv] = sy; red[2][wv] = sz; }
        __syncthreads();
        if (!t) {
            part[(b*16+chunk)*3+0] = red[0][0]+red[0][1]+red[0][2]+red[0][3];
            part[(b*16+chunk)*3+1] = red[1][0]+red[1][1]+red[1][2]+red[1][3];
            part[(b*16+chunk)*3+2] = red[2][0]+red[2][1]+red[2][2]+red[2][3];
        }
    }
}

// ---------------------------------------------------------------------------
// k_gemmA: At[b][k][o] bf16 = sum_c wgb[o][c] * feat[b][c][k], plus per-column
// stats (mu, iv) from the f32 feat values. Grid 1024 = b(4) x ktile(256).
// Block: 256 thr / 4 waves; k-tile 64, c-chunks of 64. HBM-streaming bound.
__global__ __launch_bounds__(256) void k_gemmA(
    const float* __restrict__ feat,
    const unsigned short* __restrict__ wgb,
    unsigned short* __restrict__ At,
    float2* __restrict__ stats)
{
    __shared__ float Ft[64*64];                 // [c][k] f32, 16 KB
    __shared__ unsigned short Wg[256*72];       // [o][72] bf16 pad, 36 KB
    __shared__ float sred[256], qred[256];
    int blk = blockIdx.x;
    int b = blk >> 8;
    int k0 = (blk & 255) << 6;
    int t = threadIdx.x, l = t & 63, w = t >> 6;

    f32x4 acc[4][4];
    #pragma unroll
    for (int jo = 0; jo < 4; ++jo)
        #pragma unroll
        for (int jk = 0; jk < 4; ++jk)
            acc[jo][jk] = (f32x4){0.f, 0.f, 0.f, 0.f};
    float s_acc = 0.f, q_acc = 0.f;

    const float* fb = feat + (size_t)b * D_ * K_ + k0;

    for (int c0 = 0; c0 < D_; c0 += 64) {
        __syncthreads();   // previous chunk fully consumed
        // stage feat chunk [64 c][64 k] f32 (coalesced float4)
        #pragma unroll
        for (int i = 0; i < 4; ++i) {
            int c = i*16 + (t >> 4);
            float4 v = *(const float4*)&fb[(size_t)(c0 + c) * K_ + (t & 15) * 4];
            *(float4*)&Ft[c*64 + (t & 15)*4] = v;
        }
        // stage wgb chunk [256 o][64 c] bf16 into padded [o][72]
        #pragma unroll
        for (int i = 0; i < 8; ++i) {
            int o = i*32 + (t >> 3);
            *(uint4*)&Wg[o*72 + (t & 7)*8] =
                *(const uint4*)&wgb[(size_t)o*768 + c0 + (t & 7)*8];
        }
        __syncthreads();
        // column-stats partial (f32, exact feat values)
        {
            int k = t & 63, pq = t >> 6;
            #pragma unroll
            for (int n = 0; n < 16; ++n) {
                float v = Ft[(pq*16 + n)*64 + k];
                s_acc += v; q_acc += v*v;
            }
        }
        // MFMA: mirror of verified fragment scheme (A=wgb rows, B=feat^T rows)
        #pragma unroll
        for (int kk = 0; kk < 2; ++kk) {
            int g = (kk << 2) | (l >> 4);     // granule 0..7 (8 c's each)
            bf16x8 bfr[4];
            #pragma unroll
            for (int jk = 0; jk < 4; ++jk) {
                int k = jk*16 + (l & 15);
                bf16x8 tmp;
                #pragma unroll
                for (int n = 0; n < 8; ++n)
                    tmp[n] = (short)f2bf(Ft[(g*8 + n)*64 + k]);
                bfr[jk] = tmp;
            }
            #pragma unroll
            for (int jo = 0; jo < 4; ++jo) {
                int orow = (w*4 + jo)*16 + (l & 15);
                bf16x8 a = *(const bf16x8*)&Wg[orow*72 + g*8];
                #pragma unroll
                for (int jk = 0; jk < 4; ++jk)
                    acc[jo][jk] = __builtin_amdgcn_mfma_f32_16x16x32_bf16(
                        a, bfr[jk], acc[jo][jk], 0, 0, 0);
            }
        }
    }
    // stats reduce (t = pq*64 + k)
    __syncthreads();
    sred[t] = s_acc; qred[t] = q_acc;
    __syncthreads();
    if (t < 64) {
        float S = sred[t] + sred[64+t] + sred[128+t] + sred[192+t];
        float Q = qred[t] + qred[64+t] + qred[128+t] + qred[192+t];
        float mu = S * (1.f/768.f);
        float iv = rsqrtf(Q * (1.f/768.f) - mu*mu + 1e-5f);
        stats[(size_t)b*K_ + k0 + t] = make_float2(mu, iv);
    }
    // epilogue: D row = o (A-operand), col = k (B-operand); write At bf16
    unsigned short* Ab = At + (size_t)b * K_ * 256;
    #pragma unroll
    for (int jo = 0; jo < 4; ++jo) {
        int o = (w*4 + jo)*16 + ((l >> 4) << 2);
        #pragma unroll
        for (int jk = 0; jk < 4; ++jk) {
            int k = jk*16 + (l & 15);
            ushort4 pk;
            pk.x = f2bf(acc[jo][jk][0]);
            pk.y = f2bf(acc[jo][jk][1]);
            pk.z = f2bf(acc[jo][jk][2]);
            pk.w = f2bf(acc[jo][jk][3]);
            *(ushort4*)&Ab[(size_t)(k0 + k)*256 + o] = pk;
        }
    }
}

// ---------------------------------------------------------------------------
__global__ __launch_bounds__(256) void k_cs_rad(const float* __restrict__ pc,
                                                const float* __restrict__ part,
                                                float* __restrict__ rad)
{
    int blk = blockIdx.x, b = blk >> 4, pi = blk & 15;
    float cx, cy, cz;
    reduce_center(part, b, cx, cy, cz);
    const float* p = pc + (size_t)b * N_ * 3;
    int tid = threadIdx.x;
    int i0 = pi * 1250;
    float mx = 0.f;
    for (int i = i0 + tid; i < i0 + 1250; i += 256) {
        float dx = p[i*3+0]-cx, dy = p[i*3+1]-cy, dz = p[i*3+2]-cz;
        mx = fmaxf(mx, dx*dx + dy*dy + dz*dz);
    }
    for (int off = 32; off; off >>= 1) mx = fmaxf(mx, __shfl_down(mx, off, 64));
    __shared__ float red[4];
    int w = tid >> 6, l = tid & 63;
    if (!l) red[w] = mx;
    __syncthreads();
    if (!tid) rad[b*16+pi] = fmaxf(fmaxf(red[0], red[1]), fmaxf(red[2], red[3]));
}

// ---------------------------------------------------------------------------
__global__ __launch_bounds__(256) void k_prep_pts(const float* __restrict__ pts,
                                                  const float* __restrict__ part,
                                                  const float* __restrict__ rad,
                                                  float4* __restrict__ P4)
{
    int blk = blockIdx.x, b = blk >> 6;
    float cx, cy, cz;
    reduce_center(part, b, cx, cy, cz);
    float sc = 1.f / reduce_scale(rad, b);
    int k = (blk & 63)*256 + threadIdx.x;
    const float* pp = pts + ((size_t)b*K_ + k)*3;
    float px = (pp[0]-cx)*sc, py = (pp[1]-cy)*sc, pz = (pp[2]-cz)*sc;
    P4[(size_t)b*K_ + k] = make_float4(px, py, pz, px*px + py*py + pz*pz);
}

// ---------------------------------------------------------------------------
__global__ __launch_bounds__(256) void k_nn_part(const float* __restrict__ seed_xyz,
                                                 const float4* __restrict__ P4,
                                                 const float* __restrict__ part,
                                                 const float* __restrict__ rad,
                                                 float2* __restrict__ nnp)
{
    int blk = blockIdx.x;
    int ks = blk & 3, g = (blk >> 2) & 127, b = blk >> 9;
    float cx, cy, cz;
    reduce_center(part, b, cx, cy, cz);
    float scinv = 1.f / reduce_scale(rad, b);
    int t = threadIdx.x;
    int j = t & 31, s = t >> 5;
    int m = g*8 + s;
    const float* sp = seed_xyz + ((size_t)b*M_ + m)*3;
    float sx = (sp[0]-cx)*scinv, sy = (sp[1]-cy)*scinv, sz = (sp[2]-cz)*scinv;
    float ssq = sx*sx + sy*sy + sz*sz;
    const float4* Pb = P4 + (size_t)b*K_ + ks*4096;

    float best[4] = {3.4e38f, 3.4e38f, 3.4e38f, 3.4e38f};
    int   bk[4]   = {0, 0, 0, 0};
    for (int i = 0; i < 128; i += 4) {
        #pragma unroll
        for (int r = 0; r < 4; ++r) {
            int kk = (i + r)*32 + j;
            float4 q = Pb[kk];
            float d2 = ssq + q.w - 2.f*(sx*q.x + sy*q.y + sz*q.z);
            if (d2 < best[r]) { best[r] = d2; bk[r] = kk; }
        }
    }
    float bm = best[0]; int bmk = bk[0];
    #pragma unroll
    for (int r = 1; r < 4; ++r)
        if (best[r] < bm || (best[r] == bm && bk[r] < bmk)) { bm = best[r]; bmk = bk[r]; }
    #pragma unroll
    for (int mask = 16; mask; mask >>= 1) {
        float ob = __shfl_xor(bm, mask, 64);
        int   ok = __shfl_xor(bmk, mask, 64);
        if (ob < bm || (ob == bm && ok < bmk)) { bm = ob; bmk = ok; }
    }
    if (j == 0)
        nnp[((size_t)(b*M_ + m) << 2) + ks] = make_float2(bm, __int_as_float(ks*4096 + bmk));
}

__global__ __launch_bounds__(256) void k_nn_reduce(const float2* __restrict__ nnp,
                                                   int* __restrict__ idx)
{
    int i = blockIdx.x*256 + threadIdx.x;
    float bm = 3.4e38f; int bmk = 0;
    bool first = true;
    #pragma unroll
    for (int r = 0; r < 4; ++r) {
        float2 v = nnp[((size_t)i << 2) + r];
        int k = __float_as_int(v.y);
        if (first || v.x < bm || (v.x == bm && k < bmk)) { bm = v.x; bmk = k; first = false; }
    }
    idx[i] = bmk;
}

// ---------------------------------------------------------------------------
// seed_features transpose -> fused[:, 0:256] bf16 (1024 blocks)
__global__ __launch_bounds__(256) void k_tsf(const float* __restrict__ sf,
                                             unsigned short* __restrict__ fused)
{
    __shared__ float tile[32][33];
    int id = blockIdx.x, t = threadIdx.x;
    int b = id >> 8, rem = id & 255;
    int m0 = (rem & 31) * 32, c0 = (rem >> 5) * 32;
    int tx = t & 31, ty = t >> 5;
    #pragma unroll
    for (int rr = 0; rr < 32; rr += 8)
        tile[ty+rr][tx] = sf[((size_t)b*256 + c0+ty+rr)*M_ + m0 + tx];
    __syncthreads();
    #pragma unroll
    for (int rr = 0; rr < 32; rr += 8)
        fused[((size_t)(b*M_ + m0+ty+rr))*512 + c0 + tx] = f2bf(tile[tx][ty+rr]);
}

// ---------------------------------------------------------------------------
// k_combine: h1[m][o] = relu(iv*(A[o][k] - mu*s1[o]) + bs2[o]), k=idx[m],
// written as bf16 into fused[:, 256:512]. 512 blocks = 8 seeds x 32 lanes.
__global__ __launch_bounds__(256) void k_combine(const int* __restrict__ idx,
                                                 const unsigned short* __restrict__ At,
                                                 const float2* __restrict__ stats,
                                                 const float* __restrict__ s1,
                                                 const float* __restrict__ bs2,
                                                 unsigned short* __restrict__ fused)
{
    int bid = blockIdx.x, t = threadIdx.x;
    int b = bid >> 7, grp = bid & 127;
    int j = t & 31, s = t >> 5;
    int m = grp*8 + s;
    int k = idx[b*M_ + m];
    float2 st = stats[(size_t)b*K_ + k];
    const unsigned short* arow = At + ((size_t)b*K_ + k)*256 + j*8;
    uint4 raw = *(const uint4*)arow;
    const unsigned short* rs = (const unsigned short*)&raw;
    float4 s1a = *(const float4*)&s1[j*8];
    float4 s1b = *(const float4*)&s1[j*8 + 4];
    float4 b2a = *(const float4*)&bs2[j*8];
    float4 b2b = *(const float4*)&bs2[j*8 + 4];
    float s1v[8] = {s1a.x, s1a.y, s1a.z, s1a.w, s1b.x, s1b.y, s1b.z, s1b.w};
    float b2v[8] = {b2a.x, b2a.y, b2a.z, b2a.w, b2b.x, b2b.y, b2b.z, b2b.w};
    ushort4 pk[2];
    unsigned short* po = (unsigned short*)pk;
    #pragma unroll
    for (int e = 0; e < 8; ++e) {
        float a = bf2f(rs[e]);
        float h = fmaf(st.y, a - st.x * s1v[e], b2v[e]);
        h = fmaxf(h, 0.f);
        po[e] = f2bf(h);
    }
    *(uint4*)&fused[((size_t)(b*M_ + m))*512 + 256 + j*8] = *(uint4*)pk;
}

// ---------------------------------------------------------------------------
// MFMA GEMM with double-buffered LDS (R8-verified)
__global__ __launch_bounds__(256) void k_gemm_mfma(
    const unsigned short* __restrict__ X, const unsigned short* __restrict__ W,
    const float* __restrict__ bias, int Kdim, int relu, int mode,
    unsigned short* __restrict__ Ybf, int rowStride, int colOff,
    float* __restrict__ Yf)
{
    __shared__ unsigned short Al[2][64*64];
    __shared__ unsigned short Wl[2][64*64];
    int t = threadIdx.x, l = t & 63, w = t >> 6;
    int m0 = blockIdx.x * 64, o0 = blockIdx.y * 64;
    f32x4 acc[4];
    #pragma unroll
    for (int j = 0; j < 4; ++j) acc[j] = (f32x4){0.f, 0.f, 0.f, 0.f};

    int lin0 = w*1024;
    int lb0  = lin0 + l*16;
    int row0 = lb0 >> 7;
    int ks0  = ((lb0 >> 4) & 7) ^ (row0 & 7);
    int lin1 = 4096 + w*1024;
    int lb1  = lin1 + l*16;
    int row1 = lb1 >> 7;
    int ks1  = ((lb1 >> 4) & 7) ^ (row1 & 7);

    int nt = Kdim >> 6;

    gload_lds16(X + (size_t)(m0+row0)*Kdim + ks0*8, (char*)&Al[0][0] + lin0);
    gload_lds16(W + (size_t)(o0+row0)*Kdim + ks0*8, (char*)&Wl[0][0] + lin0);
    gload_lds16(X + (size_t)(m0+row1)*Kdim + ks1*8, (char*)&Al[0][0] + lin1);
    gload_lds16(W + (size_t)(o0+row1)*Kdim + ks1*8, (char*)&Wl[0][0] + lin1);
    __syncthreads();

    for (int tt = 0; tt < nt; ++tt) {
        int cur = tt & 1;
        if (tt + 1 < nt) {
            int kc = (tt + 1) << 6;
            gload_lds16(X + (size_t)(m0+row0)*Kdim + kc + ks0*8, (char*)&Al[cur^1][0] + lin0);
            gload_lds16(W + (size_t)(o0+row0)*Kdim + kc + ks0*8, (char*)&Wl[cur^1][0] + lin0);
            gload_lds16(X + (size_t)(m0+row1)*Kdim + kc + ks1*8, (char*)&Al[cur^1][0] + lin1);
            gload_lds16(W + (size_t)(o0+row1)*Kdim + kc + ks1*8, (char*)&Wl[cur^1][0] + lin1);
        }
        #pragma unroll
        for (int kk = 0; kk < 2; ++kk) {
            int arow = w*16 + (l & 15);
            int h = l >> 4;
            bf16x8 a = *(const bf16x8*)&Al[cur][arow*64 + (((kk<<2)|h) ^ (arow & 7))*8];
            #pragma unroll
            for (int j = 0; j < 4; ++j) {
                int orow = j*16 + (l & 15);
                bf16x8 bfr = *(const bf16x8*)&Wl[cur][orow*64 + (((kk<<2)|h) ^ (orow & 7))*8];
                acc[j] = __builtin_amdgcn_mfma_f32_16x16x32_bf16(a, bfr, acc[j], 0, 0, 0);
            }
        }
        __syncthreads();
    }

    int mbase = m0 + w*16 + (l >> 4)*4;
    if (mode == 0) {
        #pragma unroll
        for (int j = 0; j < 4; ++j) {
            int o = o0 + j*16 + (l & 15);
            float bi = bias[o];
            #pragma unroll
            for (int r = 0; r < 4; ++r) {
                float v = acc[j][r] + bi;
                if (relu) v = fmaxf(v, 0.f);
                Ybf[(size_t)(mbase + r)*rowStride + colOff + o] = f2bf(v);
            }
        }
    } else {
        int b = mbase >> 10, ml = mbase & 1023;
        #pragma unroll
        for (int j = 0; j < 4; ++j) {
            int o = o0 + j*16 + (l & 15);
            float bi = bias[o];
            float4 sv = make_float4(acc[j][0]+bi, acc[j][1]+bi, acc[j][2]+bi, acc[j][3]+bi);
            *(float4*)&Yf[((size_t)(b*256 + o))*1024 + ml] = sv;
        }
    }
}

// ---------------------------------------------------------------------------
extern "C" void kernel_launch(void* const* d_in, const int* in_sizes, int n_in,
                              void* d_out, int out_size, void* d_ws, size_t ws_size,
                              hipStream_t stream)
{
    (void)in_sizes; (void)n_in; (void)out_size; (void)ws_size;
    const float* pc        = (const float*)d_in[0];
    const float* seed_xyz  = (const float*)d_in[1];
    const float* seed_feat = (const float*)d_in[2];
    const float* pts       = (const float*)d_in[3];
    const float* feat      = (const float*)d_in[4];
    const float* ln_g      = (const float*)d_in[5];
    const float* ln_b      = (const float*)d_in[6];
    const float* pw1       = (const float*)d_in[7];
    const float* pb1       = (const float*)d_in[8];
    const float* pw2       = (const float*)d_in[9];
    const float* pb2       = (const float*)d_in[10];
    const float* fw1       = (const float*)d_in[11];
    const float* fb1       = (const float*)d_in[12];
    const float* fw2       = (const float*)d_in[13];
    const float* fb2       = (const float*)d_in[14];
    float* out = (float*)d_out;

    char* ws = (char*)d_ws;
    float*          part  = (float*)(ws + OFF_PART);
    float*          rad   = (float*)(ws + OFF_RAD);
    int*            idx   = (int*)(ws + OFF_IDX);
    float4*         P4    = (float4*)(ws + OFF_P4);
    float2*         nnp   = (float2*)(ws + OFF_NNP);
    float2*         stats = (float2*)(ws + OFF_STATS);
    unsigned short* At    = (unsigned short*)(ws + OFF_AT);
    unsigned short* fused = (unsigned short*)(ws + OFF_FUSED);
    unsigned short* h2    = (unsigned short*)(ws + OFF_H2);
    unsigned short* wgb   = (unsigned short*)(ws + OFF_WGB);
    unsigned short* Wcat  = (unsigned short*)(ws + OFF_WCAT);
    unsigned short* Wb4   = (unsigned short*)(ws + OFF_WB4);
    float*          bc    = (float*)(ws + OFF_BC);
    float*          s1    = (float*)(ws + OFF_S1);
    float*          bs2   = (float*)(ws + OFF_BS2);

    k_pre<<<832, 256, 0, stream>>>(pc, pw1, pw2, pb1, pb2, fw1, fb1, fw2,
                                   ln_g, ln_b, wgb, Wcat, Wb4, bc, s1, bs2, part);
    k_gemmA<<<1024, 256, 0, stream>>>(feat, wgb, At, stats);
    k_cs_rad<<<64, 256, 0, stream>>>(pc, part, rad);
    k_prep_pts<<<256, 256, 0, stream>>>(pts, part, rad, P4);
    k_nn_part<<<2048, 256, 0, stream>>>(seed_xyz, P4, part, rad, nnp);
    k_nn_reduce<<<16, 256, 0, stream>>>(nnp, idx);
    k_tsf<<<1024, 256, 0, stream>>>(seed_feat, fused);
    k_combine<<<512, 256, 0, stream>>>(idx, At, stats, s1, bs2, fused);
    // gemm3': h2 = relu(Wcat @ fused + bc)
    k_gemm_mfma<<<dim3(64, 4), 256, 0, stream>>>(fused, Wcat, bc, 512, 1, 0, h2, 256, 0, nullptr);
    // gemm4: out = fw2 @ h2 + fb2 -> f32 [B][256][M]
    k_gemm_mfma<<<dim3(64, 4), 256, 0, stream>>>(h2, Wb4, fb2, 256, 0, 1, nullptr, 0, 0, out);
}

// Round 12
// 149.723 us; speedup vs baseline: 1.3467x; 1.3467x over previous
//
#include <hip/hip_runtime.h>
#include <math.h>

#define B_ 4
#define N_ 20000
#define M_ 1024
#define K_ 16384
#define D_ 768

typedef __attribute__((ext_vector_type(8))) short bf16x8;
typedef __attribute__((ext_vector_type(4))) float f32x4;

// Workspace offsets (ws is 768 MiB)
#define OFF_PART   0ul          // f32 [4][16][3] partial sums
#define OFF_RAD    1024ul       // f32 [4][16] partial max radius^2
#define OFF_IDX    4096ul       // int [4][1024]
#define OFF_P4     32768ul      // float4 [4][16384] normalized pts (1 MB)
#define OFF_NNP    1179648ul    // float2 [4][1024][4] NN partials (128 KB)
#define OFF_G      2097152ul    // f32 [4][768][1024]  (12.58 MB)
#define OFF_XLN    16777216ul   // bf16 [4096][768]
#define OFF_FUSED  25165824ul   // bf16 [4096][512]
#define OFF_H2     29360128ul   // bf16 [4096][256]
#define OFF_WB1    33554432ul   // bf16 [256][768]
#define OFF_WCAT   34603008ul   // bf16 [256][512]
#define OFF_WB4    35651584ul   // bf16 [256][256]
#define OFF_BC     36700160ul   // f32 [256]

__device__ inline unsigned short f2bf(float x) {
    union { float f; unsigned int u; } v; v.f = x;
    unsigned int r = v.u + 0x7fffu + ((v.u >> 16) & 1u);
    return (unsigned short)(r >> 16);
}

__device__ inline void gload_lds16(const void* g, void* lds) {
    __builtin_amdgcn_global_load_lds(
        (const __attribute__((address_space(1))) unsigned int*)g,
        (__attribute__((address_space(3))) unsigned int*)lds, 16, 0, 0);
}

__device__ inline void reduce_center(const float* part, int b,
                                     float& cx, float& cy, float& cz)
{
    cx = 0.f; cy = 0.f; cz = 0.f;
    #pragma unroll
    for (int r = 0; r < 16; ++r) {
        cx += part[(b*16+r)*3+0];
        cy += part[(b*16+r)*3+1];
        cz += part[(b*16+r)*3+2];
    }
    cx *= (1.f/N_); cy *= (1.f/N_); cz *= (1.f/N_);
}

__device__ inline float reduce_scale(const float* rad, int b)
{
    float m = 0.f;
    #pragma unroll
    for (int r = 0; r < 16; ++r) m = fmaxf(m, rad[b*16+r]);
    return fmaxf(sqrtf(m), 1e-6f);
}

// ---------------------------------------------------------------------------
// k_pre: weight cvt (bid<768) + Wcat-fold/bc (bid<256) + cs_sum (bid>=768)
__global__ __launch_bounds__(256) void k_pre(
    const float* __restrict__ pc,
    const float* __restrict__ pw1, const float* __restrict__ pw2,
    const float* __restrict__ pb2,
    const float* __restrict__ fw1, const float* __restrict__ fb1,
    const float* __restrict__ fw2,
    unsigned short* __restrict__ Wb1, unsigned short* __restrict__ Wcat,
    unsigned short* __restrict__ Wb4, float* __restrict__ bc,
    float* __restrict__ part)
{
    int bid = blockIdx.x, t = threadIdx.x;
    int lane = t & 63, wv = t >> 6;
    __shared__ float red[3][4];

    if (bid < 768) {
        int i0 = bid*256 + t;
        Wb1[i0] = f2bf(pw1[i0]);
        if (i0 < 65536) {
            int o = i0 >> 8, c = i0 & 255;
            Wcat[(size_t)o*512 + c] = f2bf(fw1[(size_t)o*512 + c]);
            Wb4[i0] = f2bf(fw2[i0]);
        }
    }
    if (bid < 256) {
        const float* fb = fw1 + (size_t)bid*512 + 256;
        float acc = 0.f;
        for (int j = 0; j < 256; ++j)
            acc = fmaf(fb[j], pw2[j*256 + t], acc);
        Wcat[(size_t)bid*512 + 256 + t] = f2bf(acc);
        float v = fb[t] * pb2[t];
        for (int off = 32; off; off >>= 1) v += __shfl_down(v, off, 64);
        if (!lane) red[0][wv] = v;
        __syncthreads();
        if (!t) bc[bid] = red[0][0]+red[0][1]+red[0][2]+red[0][3] + fb1[bid];
    } else if (bid >= 768) {
        int pi = bid - 768;
        int b = pi >> 4, chunk = pi & 15;
        const float* p = pc + (size_t)b * N_ * 3;
        int i0 = chunk * 1250;
        float sx = 0.f, sy = 0.f, sz = 0.f;
        for (int i = i0 + t; i < i0 + 1250; i += 256) {
            sx += p[i*3+0]; sy += p[i*3+1]; sz += p[i*3+2];
        }
        for (int off = 32; off; off >>= 1) {
            sx += __shfl_down(sx, off, 64);
            sy += __shfl_down(sy, off, 64);
            sz += __shfl_down(sz, off, 64);
        }
        if (!lane) { red[0][wv] = sx; red[1][wv] = sy; red[2][wv] = sz; }
        __syncthreads();
        if (!t) {
            part[(b*16+chunk)*3+0] = red[0][0]+red[0][1]+red[0][2]+red[0][3];
            part[(b*16+chunk)*3+1] = red[1][0]+red[1][1]+red[1][2]+red[1][3];
            part[(b*16+chunk)*3+2] = red[2][0]+red[2][1]+red[2][2]+red[2][3];
        }
    }
}

// ---------------------------------------------------------------------------
__global__ __launch_bounds__(256) void k_cs_rad(const float* __restrict__ pc,
                                                const float* __restrict__ part,
                                                float* __restrict__ rad)
{
    int blk = blockIdx.x, b = blk >> 4, pi = blk & 15;
    float cx, cy, cz;
    reduce_center(part, b, cx, cy, cz);
    const float* p = pc + (size_t)b * N_ * 3;
    int tid = threadIdx.x;
    int i0 = pi * 1250;
    float mx = 0.f;
    for (int i = i0 + tid; i < i0 + 1250; i += 256) {
        float dx = p[i*3+0]-cx, dy = p[i*3+1]-cy, dz = p[i*3+2]-cz;
        mx = fmaxf(mx, dx*dx + dy*dy + dz*dz);
    }
    for (int off = 32; off; off >>= 1) mx = fmaxf(mx, __shfl_down(mx, off, 64));
    __shared__ float red[4];
    int w = tid >> 6, l = tid & 63;
    if (!l) red[w] = mx;
    __syncthreads();
    if (!tid) rad[b*16+pi] = fmaxf(fmaxf(red[0], red[1]), fmaxf(red[2], red[3]));
}

// ---------------------------------------------------------------------------
// normalize pts -> float4(nx,ny,nz,|n|^2)
__global__ __launch_bounds__(256) void k_prep_pts(const float* __restrict__ pts,
                                                  const float* __restrict__ part,
                                                  const float* __restrict__ rad,
                                                  float4* __restrict__ P4)
{
    int blk = blockIdx.x, b = blk >> 6;
    float cx, cy, cz;
    reduce_center(part, b, cx, cy, cz);
    float sc = 1.f / reduce_scale(rad, b);
    int k = (blk & 63)*256 + threadIdx.x;
    const float* pp = pts + ((size_t)b*K_ + k)*3;
    float px = (pp[0]-cx)*sc, py = (pp[1]-cy)*sc, pz = (pp[2]-cz)*sc;
    P4[(size_t)b*K_ + k] = make_float4(px, py, pz, px*px + py*py + pz*pz);
}

// ---------------------------------------------------------------------------
// NN partial argmin: K split x4. Grid 2048 = [b:4][g:128][ks:4].
__global__ __launch_bounds__(256) void k_nn_part(const float* __restrict__ seed_xyz,
                                                 const float4* __restrict__ P4,
                                                 const float* __restrict__ part,
                                                 const float* __restrict__ rad,
                                                 float2* __restrict__ nnp)
{
    int blk = blockIdx.x;
    int ks = blk & 3, g = (blk >> 2) & 127, b = blk >> 9;
    float cx, cy, cz;
    reduce_center(part, b, cx, cy, cz);
    float scinv = 1.f / reduce_scale(rad, b);
    int t = threadIdx.x;
    int j = t & 31, s = t >> 5;
    int m = g*8 + s;
    const float* sp = seed_xyz + ((size_t)b*M_ + m)*3;
    float sx = (sp[0]-cx)*scinv, sy = (sp[1]-cy)*scinv, sz = (sp[2]-cz)*scinv;
    float ssq = sx*sx + sy*sy + sz*sz;
    const float4* Pb = P4 + (size_t)b*K_ + ks*4096;

    float best[4] = {3.4e38f, 3.4e38f, 3.4e38f, 3.4e38f};
    int   bk[4]   = {0, 0, 0, 0};
    for (int i = 0; i < 128; i += 4) {
        #pragma unroll
        for (int r = 0; r < 4; ++r) {
            int kk = (i + r)*32 + j;
            float4 q = Pb[kk];
            float d2 = ssq + q.w - 2.f*(sx*q.x + sy*q.y + sz*q.z);
            if (d2 < best[r]) { best[r] = d2; bk[r] = kk; }
        }
    }
    float bm = best[0]; int bmk = bk[0];
    #pragma unroll
    for (int r = 1; r < 4; ++r)
        if (best[r] < bm || (best[r] == bm && bk[r] < bmk)) { bm = best[r]; bmk = bk[r]; }
    #pragma unroll
    for (int mask = 16; mask; mask >>= 1) {
        float ob = __shfl_xor(bm, mask, 64);
        int   ok = __shfl_xor(bmk, mask, 64);
        if (ob < bm || (ob == bm && ok < bmk)) { bm = ob; bmk = ok; }
    }
    if (j == 0)
        nnp[((size_t)(b*M_ + m) << 2) + ks] = make_float2(bm, __int_as_float(ks*4096 + bmk));
}

// Final merge over the 4 K-chunks (in order -> ties pick lower chunk = lower k)
__global__ __launch_bounds__(256) void k_nn_reduce(const float2* __restrict__ nnp,
                                                   int* __restrict__ idx)
{
    int i = blockIdx.x*256 + threadIdx.x;
    float bm = 3.4e38f; int bmk = 0;
    bool first = true;
    #pragma unroll
    for (int r = 0; r < 4; ++r) {
        float2 v = nnp[((size_t)i << 2) + r];
        int k = __float_as_int(v.y);
        if (first || v.x < bm || (v.x == bm && k < bmk)) { bm = v.x; bmk = k; first = false; }
    }
    idx[i] = bmk;
}

// ---------------------------------------------------------------------------
// LDS-staged streaming gather: one block per (b,c) row. Stream the whole
// 64KB feat row into LDS with sequential 1KB-per-wave global_load_lds bursts
// (full streaming DRAM efficiency, guaranteed residence), then the 1024
// random reads hit LDS (random 4B reads ~2 lanes/bank = near-free).
// Values identical to direct gather.
__global__ __launch_bounds__(256) void k_gather_row(const float* __restrict__ feat,
                                                    const int* __restrict__ idx,
                                                    float* __restrict__ G)
{
    __shared__ float L[16384];     // 64 KB -> 2 blocks/CU
    int bid = blockIdx.x;          // 0..3071
    int b = bid / 768, c = bid - b*768;
    const float* frow = feat + ((size_t)b*D_ + c) * K_;
    int t = threadIdx.x, l = t & 63, w = t >> 6;

    // wave w stages floats [w*4096, (w+1)*4096): 16 bursts of 1KB
    const float* src = frow + w*4096 + l*4;
    char* dst = (char*)L + w*16384;
    #pragma unroll
    for (int it = 0; it < 16; ++it)
        gload_lds16(src + it*256, dst + it*1024);
    __syncthreads();               // drains vmcnt before barrier

    const int* ib = idx + b*M_;
    float* grow = G + ((size_t)b*D_ + c) * M_;
    #pragma unroll
    for (int r = 0; r < 4; ++r) {
        int m = r*256 + t;
        grow[m] = L[ib[m]];
    }
}

// ---------------------------------------------------------------------------
// seed_features transpose -> fused[:, 0:256] bf16 (1024 blocks)
__global__ __launch_bounds__(256) void k_tsf(const float* __restrict__ sf,
                                             unsigned short* __restrict__ fused)
{
    __shared__ float tile[32][33];
    int id = blockIdx.x, t = threadIdx.x;
    int b = id >> 8, rem = id & 255;
    int m0 = (rem & 31) * 32, c0 = (rem >> 5) * 32;
    int tx = t & 31, ty = t >> 5;
    #pragma unroll
    for (int rr = 0; rr < 32; rr += 8)
        tile[ty+rr][tx] = sf[((size_t)b*256 + c0+ty+rr)*M_ + m0 + tx];
    __syncthreads();
    #pragma unroll
    for (int rr = 0; rr < 32; rr += 8)
        fused[((size_t)(b*M_ + m0+ty+rr))*512 + c0 + tx] = f2bf(tile[tx][ty+rr]);
}

// ---------------------------------------------------------------------------
// fused LN: stats + apply + transpose -> xln bf16 [b][m][c]  (R8-verified)
__global__ __launch_bounds__(256) void k_ln_fused(const float* __restrict__ G,
                                                  const float* __restrict__ gamma,
                                                  const float* __restrict__ beta,
                                                  unsigned short* __restrict__ xln)
{
    int b = blockIdx.y, m0 = blockIdx.x * 32;
    int t = threadIdx.x;
    int ml = t & 31, cp = t >> 5;
    const float* Gb = G + (size_t)b * D_ * M_;
    float s = 0.f, q = 0.f;
    for (int c = cp; c < D_; c += 8) {
        float v = Gb[(size_t)c*M_ + m0 + ml];
        s += v; q += v*v;
    }
    __shared__ float sred[8][32], qred[8][32];
    __shared__ float mu[32], iv[32];
    sred[cp][ml] = s; qred[cp][ml] = q;
    __syncthreads();
    if (t < 32) {
        float S = 0.f, Q = 0.f;
        #pragma unroll
        for (int r = 0; r < 8; ++r) { S += sred[r][t]; Q += qred[r][t]; }
        float m_ = S * (1.f/768.f);
        mu[t] = m_;
        iv[t] = rsqrtf(Q * (1.f/768.f) - m_*m_ + 1e-5f);
    }
    __syncthreads();

    __shared__ float tile[64][33];
    int ty = t >> 5;
    int cx2 = t & 31;
    for (int c0 = 0; c0 < D_; c0 += 64) {
        __syncthreads();
        #pragma unroll
        for (int ri = 0; ri < 8; ++ri) {
            int cl = ty*8 + ri;
            tile[cl][ml] = Gb[(size_t)(c0+cl)*M_ + m0 + ml];
        }
        __syncthreads();
        float2 ga = *(const float2*)&gamma[c0 + 2*cx2];
        float2 be = *(const float2*)&beta[c0 + 2*cx2];
        #pragma unroll
        for (int ri = 0; ri < 4; ++ri) {
            int m_l = ty*4 + ri;
            float v0 = (tile[2*cx2+0][m_l] - mu[m_l]) * iv[m_l] * ga.x + be.x;
            float v1 = (tile[2*cx2+1][m_l] - mu[m_l]) * iv[m_l] * ga.y + be.y;
            ushort2 pk = make_ushort2(f2bf(v0), f2bf(v1));
            *(ushort2*)&xln[((size_t)((b<<10) + m0 + m_l))*D_ + c0 + 2*cx2] = pk;
        }
    }
}

// ---------------------------------------------------------------------------
// MFMA GEMM with double-buffered LDS (R8-verified)
__global__ __launch_bounds__(256) void k_gemm_mfma(
    const unsigned short* __restrict__ X, const unsigned short* __restrict__ W,
    const float* __restrict__ bias, int Kdim, int relu, int mode,
    unsigned short* __restrict__ Ybf, int rowStride, int colOff,
    float* __restrict__ Yf)
{
    __shared__ unsigned short Al[2][64*64];
    __shared__ unsigned short Wl[2][64*64];
    int t = threadIdx.x, l = t & 63, w = t >> 6;
    int m0 = blockIdx.x * 64, o0 = blockIdx.y * 64;
    f32x4 acc[4];
    #pragma unroll
    for (int j = 0; j < 4; ++j) acc[j] = (f32x4){0.f, 0.f, 0.f, 0.f};

    int lin0 = w*1024;
    int lb0  = lin0 + l*16;
    int row0 = lb0 >> 7;
    int ks0  = ((lb0 >> 4) & 7) ^ (row0 & 7);
    int lin1 = 4096 + w*1024;
    int lb1  = lin1 + l*16;
    int row1 = lb1 >> 7;
    int ks1  = ((lb1 >> 4) & 7) ^ (row1 & 7);

    int nt = Kdim >> 6;

    gload_lds16(X + (size_t)(m0+row0)*Kdim + ks0*8, (char*)&Al[0][0] + lin0);
    gload_lds16(W + (size_t)(o0+row0)*Kdim + ks0*8, (char*)&Wl[0][0] + lin0);
    gload_lds16(X + (size_t)(m0+row1)*Kdim + ks1*8, (char*)&Al[0][0] + lin1);
    gload_lds16(W + (size_t)(o0+row1)*Kdim + ks1*8, (char*)&Wl[0][0] + lin1);
    __syncthreads();

    for (int tt = 0; tt < nt; ++tt) {
        int cur = tt & 1;
        if (tt + 1 < nt) {
            int kc = (tt + 1) << 6;
            gload_lds16(X + (size_t)(m0+row0)*Kdim + kc + ks0*8, (char*)&Al[cur^1][0] + lin0);
            gload_lds16(W + (size_t)(o0+row0)*Kdim + kc + ks0*8, (char*)&Wl[cur^1][0] + lin0);
            gload_lds16(X + (size_t)(m0+row1)*Kdim + kc + ks1*8, (char*)&Al[cur^1][0] + lin1);
            gload_lds16(W + (size_t)(o0+row1)*Kdim + kc + ks1*8, (char*)&Wl[cur^1][0] + lin1);
        }
        #pragma unroll
        for (int kk = 0; kk < 2; ++kk) {
            int arow = w*16 + (l & 15);
            int h = l >> 4;
            bf16x8 a = *(const bf16x8*)&Al[cur][arow*64 + (((kk<<2)|h) ^ (arow & 7))*8];
            #pragma unroll
            for (int j = 0; j < 4; ++j) {
                int orow = j*16 + (l & 15);
                bf16x8 bfr = *(const bf16x8*)&Wl[cur][orow*64 + (((kk<<2)|h) ^ (orow & 7))*8];
                acc[j] = __builtin_amdgcn_mfma_f32_16x16x32_bf16(a, bfr, acc[j], 0, 0, 0);
            }
        }
        __syncthreads();
    }

    int mbase = m0 + w*16 + (l >> 4)*4;
    if (mode == 0) {
        #pragma unroll
        for (int j = 0; j < 4; ++j) {
            int o = o0 + j*16 + (l & 15);
            float bi = bias[o];
            #pragma unroll
            for (int r = 0; r < 4; ++r) {
                float v = acc[j][r] + bi;
                if (relu) v = fmaxf(v, 0.f);
                Ybf[(size_t)(mbase + r)*rowStride + colOff + o] = f2bf(v);
            }
        }
    } else {
        int b = mbase >> 10, ml = mbase & 1023;
        #pragma unroll
        for (int j = 0; j < 4; ++j) {
            int o = o0 + j*16 + (l & 15);
            float bi = bias[o];
            float4 sv = make_float4(acc[j][0]+bi, acc[j][1]+bi, acc[j][2]+bi, acc[j][3]+bi);
            *(float4*)&Yf[((size_t)(b*256 + o))*1024 + ml] = sv;
        }
    }
}

// ---------------------------------------------------------------------------
extern "C" void kernel_launch(void* const* d_in, const int* in_sizes, int n_in,
                              void* d_out, int out_size, void* d_ws, size_t ws_size,
                              hipStream_t stream)
{
    (void)in_sizes; (void)n_in; (void)out_size; (void)ws_size;
    const float* pc        = (const float*)d_in[0];
    const float* seed_xyz  = (const float*)d_in[1];
    const float* seed_feat = (const float*)d_in[2];
    const float* pts       = (const float*)d_in[3];
    const float* feat      = (const float*)d_in[4];
    const float* ln_g      = (const float*)d_in[5];
    const float* ln_b      = (const float*)d_in[6];
    const float* pw1       = (const float*)d_in[7];
    const float* pb1       = (const float*)d_in[8];
    const float* pw2       = (const float*)d_in[9];
    const float* pb2       = (const float*)d_in[10];
    const float* fw1       = (const float*)d_in[11];
    const float* fb1       = (const float*)d_in[12];
    const float* fw2       = (const float*)d_in[13];
    const float* fb2       = (const float*)d_in[14];
    float* out = (float*)d_out;

    char* ws = (char*)d_ws;
    float*          part  = (float*)(ws + OFF_PART);
    float*          rad   = (float*)(ws + OFF_RAD);
    int*            idx   = (int*)(ws + OFF_IDX);
    float4*         P4    = (float4*)(ws + OFF_P4);
    float2*         nnp   = (float2*)(ws + OFF_NNP);
    float*          G     = (float*)(ws + OFF_G);
    unsigned short* xln   = (unsigned short*)(ws + OFF_XLN);
    unsigned short* fused = (unsigned short*)(ws + OFF_FUSED);
    unsigned short* h2    = (unsigned short*)(ws + OFF_H2);
    unsigned short* Wb1   = (unsigned short*)(ws + OFF_WB1);
    unsigned short* Wcat  = (unsigned short*)(ws + OFF_WCAT);
    unsigned short* Wb4   = (unsigned short*)(ws + OFF_WB4);
    float*          bc    = (float*)(ws + OFF_BC);

    k_pre<<<832, 256, 0, stream>>>(pc, pw1, pw2, pb2, fw1, fb1, fw2,
                                   Wb1, Wcat, Wb4, bc, part);
    k_cs_rad<<<64, 256, 0, stream>>>(pc, part, rad);
    k_prep_pts<<<256, 256, 0, stream>>>(pts, part, rad, P4);
    k_nn_part<<<2048, 256, 0, stream>>>(seed_xyz, P4, part, rad, nnp);
    k_nn_reduce<<<16, 256, 0, stream>>>(nnp, idx);
    k_gather_row<<<3072, 256, 0, stream>>>(feat, idx, G);
    k_tsf<<<1024, 256, 0, stream>>>(seed_feat, fused);
    k_ln_fused<<<dim3(M_/32, B_), 256, 0, stream>>>(G, ln_g, ln_b, xln);
    // gemm1: fused[:,256:512] = relu(pw1 @ xln + pb1)
    k_gemm_mfma<<<dim3(64, 4), 256, 0, stream>>>(xln, Wb1, pb1, 768, 1, 0, fused, 512, 256, nullptr);
    // gemm3': h2 = relu(Wcat @ fused + bc)
    k_gemm_mfma<<<dim3(64, 4), 256, 0, stream>>>(fused, Wcat, bc, 512, 1, 0, h2, 256, 0, nullptr);
    // gemm4: out = fw2 @ h2 + fb2 -> f32 [B][256][M]
    k_gemm_mfma<<<dim3(64, 4), 256, 0, stream>>>(h2, Wb4, fb2, 256, 0, 1, nullptr, 0, 0, out);
}

// Round 13
// 147.866 us; speedup vs baseline: 1.3636x; 1.0126x over previous
//
#include <hip/hip_runtime.h>
#include <math.h>

#define B_ 4
#define N_ 20000
#define M_ 1024
#define K_ 16384
#define D_ 768

typedef __attribute__((ext_vector_type(8))) short bf16x8;
typedef __attribute__((ext_vector_type(4))) float f32x4;

// Workspace offsets (ws is 768 MiB)
#define OFF_PART   0ul          // f32 [4][16][3] partial sums
#define OFF_RAD    1024ul       // f32 [4][16] partial max radius^2
#define OFF_IDX    4096ul       // int [4][1024]
#define OFF_P4     32768ul      // float4 [4][16384] normalized pts (1 MB)
#define OFF_NNP    1179648ul    // float2 [4][1024][4] NN partials (128 KB)
#define OFF_G      2097152ul    // f32 [4][768][1024]  (12.58 MB)
#define OFF_XLN    16777216ul   // bf16 [4096][768]
#define OFF_FUSED  25165824ul   // bf16 [4096][512]
#define OFF_H2     29360128ul   // bf16 [4096][256]
#define OFF_WB1    33554432ul   // bf16 [256][768]
#define OFF_WCAT   34603008ul   // bf16 [256][512]
#define OFF_WB4    35651584ul   // bf16 [256][256]
#define OFF_BC     36700160ul   // f32 [256]

__device__ inline unsigned short f2bf(float x) {
    union { float f; unsigned int u; } v; v.f = x;
    unsigned int r = v.u + 0x7fffu + ((v.u >> 16) & 1u);
    return (unsigned short)(r >> 16);
}

__device__ inline void gload_lds16(const void* g, void* lds) {
    __builtin_amdgcn_global_load_lds(
        (const __attribute__((address_space(1))) unsigned int*)g,
        (__attribute__((address_space(3))) unsigned int*)lds, 16, 0, 0);
}

__device__ inline void reduce_center(const float* part, int b,
                                     float& cx, float& cy, float& cz)
{
    cx = 0.f; cy = 0.f; cz = 0.f;
    #pragma unroll
    for (int r = 0; r < 16; ++r) {
        cx += part[(b*16+r)*3+0];
        cy += part[(b*16+r)*3+1];
        cz += part[(b*16+r)*3+2];
    }
    cx *= (1.f/N_); cy *= (1.f/N_); cz *= (1.f/N_);
}

__device__ inline float reduce_scale(const float* rad, int b)
{
    float m = 0.f;
    #pragma unroll
    for (int r = 0; r < 16; ++r) m = fmaxf(m, rad[b*16+r]);
    return fmaxf(sqrtf(m), 1e-6f);
}

// ---------------------------------------------------------------------------
// k_pre: weight cvt (bid<768) + Wcat-fold/bc (bid<256) + cs_sum (bid>=768)
__global__ __launch_bounds__(256) void k_pre(
    const float* __restrict__ pc,
    const float* __restrict__ pw1, const float* __restrict__ pw2,
    const float* __restrict__ pb2,
    const float* __restrict__ fw1, const float* __restrict__ fb1,
    const float* __restrict__ fw2,
    unsigned short* __restrict__ Wb1, unsigned short* __restrict__ Wcat,
    unsigned short* __restrict__ Wb4, float* __restrict__ bc,
    float* __restrict__ part)
{
    int bid = blockIdx.x, t = threadIdx.x;
    int lane = t & 63, wv = t >> 6;
    __shared__ float red[3][4];

    if (bid < 768) {
        int i0 = bid*256 + t;
        Wb1[i0] = f2bf(pw1[i0]);
        if (i0 < 65536) {
            int o = i0 >> 8, c = i0 & 255;
            Wcat[(size_t)o*512 + c] = f2bf(fw1[(size_t)o*512 + c]);
            Wb4[i0] = f2bf(fw2[i0]);
        }
    }
    if (bid < 256) {
        const float* fb = fw1 + (size_t)bid*512 + 256;
        float acc = 0.f;
        for (int j = 0; j < 256; ++j)
            acc = fmaf(fb[j], pw2[j*256 + t], acc);
        Wcat[(size_t)bid*512 + 256 + t] = f2bf(acc);
        float v = fb[t] * pb2[t];
        for (int off = 32; off; off >>= 1) v += __shfl_down(v, off, 64);
        if (!lane) red[0][wv] = v;
        __syncthreads();
        if (!t) bc[bid] = red[0][0]+red[0][1]+red[0][2]+red[0][3] + fb1[bid];
    } else if (bid >= 768) {
        int pi = bid - 768;
        int b = pi >> 4, chunk = pi & 15;
        const float* p = pc + (size_t)b * N_ * 3;
        int i0 = chunk * 1250;
        float sx = 0.f, sy = 0.f, sz = 0.f;
        for (int i = i0 + t; i < i0 + 1250; i += 256) {
            sx += p[i*3+0]; sy += p[i*3+1]; sz += p[i*3+2];
        }
        for (int off = 32; off; off >>= 1) {
            sx += __shfl_down(sx, off, 64);
            sy += __shfl_down(sy, off, 64);
            sz += __shfl_down(sz, off, 64);
        }
        if (!lane) { red[0][wv] = sx; red[1][wv] = sy; red[2][wv] = sz; }
        __syncthreads();
        if (!t) {
            part[(b*16+chunk)*3+0] = red[0][0]+red[0][1]+red[0][2]+red[0][3];
            part[(b*16+chunk)*3+1] = red[1][0]+red[1][1]+red[1][2]+red[1][3];
            part[(b*16+chunk)*3+2] = red[2][0]+red[2][1]+red[2][2]+red[2][3];
        }
    }
}

// ---------------------------------------------------------------------------
__global__ __launch_bounds__(256) void k_cs_rad(const float* __restrict__ pc,
                                                const float* __restrict__ part,
                                                float* __restrict__ rad)
{
    int blk = blockIdx.x, b = blk >> 4, pi = blk & 15;
    float cx, cy, cz;
    reduce_center(part, b, cx, cy, cz);
    const float* p = pc + (size_t)b * N_ * 3;
    int tid = threadIdx.x;
    int i0 = pi * 1250;
    float mx = 0.f;
    for (int i = i0 + tid; i < i0 + 1250; i += 256) {
        float dx = p[i*3+0]-cx, dy = p[i*3+1]-cy, dz = p[i*3+2]-cz;
        mx = fmaxf(mx, dx*dx + dy*dy + dz*dz);
    }
    for (int off = 32; off; off >>= 1) mx = fmaxf(mx, __shfl_down(mx, off, 64));
    __shared__ float red[4];
    int w = tid >> 6, l = tid & 63;
    if (!l) red[w] = mx;
    __syncthreads();
    if (!tid) rad[b*16+pi] = fmaxf(fmaxf(red[0], red[1]), fmaxf(red[2], red[3]));
}

// ---------------------------------------------------------------------------
// normalize pts -> float4(nx,ny,nz,|n|^2)
__global__ __launch_bounds__(256) void k_prep_pts(const float* __restrict__ pts,
                                                  const float* __restrict__ part,
                                                  const float* __restrict__ rad,
                                                  float4* __restrict__ P4)
{
    int blk = blockIdx.x, b = blk >> 6;
    float cx, cy, cz;
    reduce_center(part, b, cx, cy, cz);
    float sc = 1.f / reduce_scale(rad, b);
    int k = (blk & 63)*256 + threadIdx.x;
    const float* pp = pts + ((size_t)b*K_ + k)*3;
    float px = (pp[0]-cx)*sc, py = (pp[1]-cy)*sc, pz = (pp[2]-cz)*sc;
    P4[(size_t)b*K_ + k] = make_float4(px, py, pz, px*px + py*py + pz*pz);
}

// ---------------------------------------------------------------------------
// NN partial argmin: K split x4. Grid 2048 = [b:4][g:128][ks:4].
__global__ __launch_bounds__(256) void k_nn_part(const float* __restrict__ seed_xyz,
                                                 const float4* __restrict__ P4,
                                                 const float* __restrict__ part,
                                                 const float* __restrict__ rad,
                                                 float2* __restrict__ nnp)
{
    int blk = blockIdx.x;
    int ks = blk & 3, g = (blk >> 2) & 127, b = blk >> 9;
    float cx, cy, cz;
    reduce_center(part, b, cx, cy, cz);
    float scinv = 1.f / reduce_scale(rad, b);
    int t = threadIdx.x;
    int j = t & 31, s = t >> 5;
    int m = g*8 + s;
    const float* sp = seed_xyz + ((size_t)b*M_ + m)*3;
    float sx = (sp[0]-cx)*scinv, sy = (sp[1]-cy)*scinv, sz = (sp[2]-cz)*scinv;
    float ssq = sx*sx + sy*sy + sz*sz;
    const float4* Pb = P4 + (size_t)b*K_ + ks*4096;

    float best[4] = {3.4e38f, 3.4e38f, 3.4e38f, 3.4e38f};
    int   bk[4]   = {0, 0, 0, 0};
    for (int i = 0; i < 128; i += 4) {
        #pragma unroll
        for (int r = 0; r < 4; ++r) {
            int kk = (i + r)*32 + j;
            float4 q = Pb[kk];
            float d2 = ssq + q.w - 2.f*(sx*q.x + sy*q.y + sz*q.z);
            if (d2 < best[r]) { best[r] = d2; bk[r] = kk; }
        }
    }
    float bm = best[0]; int bmk = bk[0];
    #pragma unroll
    for (int r = 1; r < 4; ++r)
        if (best[r] < bm || (best[r] == bm && bk[r] < bmk)) { bm = best[r]; bmk = bk[r]; }
    #pragma unroll
    for (int mask = 16; mask; mask >>= 1) {
        float ob = __shfl_xor(bm, mask, 64);
        int   ok = __shfl_xor(bmk, mask, 64);
        if (ob < bm || (ob == bm && ok < bmk)) { bm = ob; bmk = ok; }
    }
    if (j == 0)
        nnp[((size_t)(b*M_ + m) << 2) + ks] = make_float2(bm, __int_as_float(ks*4096 + bmk));
}

// Final merge over the 4 K-chunks (in order -> ties pick lower chunk = lower k)
__global__ __launch_bounds__(256) void k_nn_reduce(const float2* __restrict__ nnp,
                                                   int* __restrict__ idx)
{
    int i = blockIdx.x*256 + threadIdx.x;
    float bm = 3.4e38f; int bmk = 0;
    bool first = true;
    #pragma unroll
    for (int r = 0; r < 4; ++r) {
        float2 v = nnp[((size_t)i << 2) + r];
        int k = __float_as_int(v.y);
        if (first || v.x < bm || (v.x == bm && k < bmk)) { bm = v.x; bmk = k; first = false; }
    }
    idx[i] = bmk;
}

// ---------------------------------------------------------------------------
// gather: bid<768 -> FOUR channel rows per block (16 scattered loads in
// flight, idx loaded once); bid>=768 -> seed-feature transpose tiles.
__global__ __launch_bounds__(256) void k_gather_tsf(const float* __restrict__ feat,
                                                    const int* __restrict__ idx,
                                                    const float* __restrict__ sf,
                                                    float* __restrict__ G,
                                                    unsigned short* __restrict__ fused)
{
    int bid = blockIdx.x, t = threadIdx.x;
    if (bid < 768) {
        int b = bid / 192;
        int c = (bid - b*192) * 4;
        const float* frow = feat + ((size_t)b*D_ + c) * K_;
        const int* ib = idx + b*M_;
        float* grow = G + ((size_t)b*D_ + c) * M_;
        int id4[4];
        #pragma unroll
        for (int r = 0; r < 4; ++r) id4[r] = ib[r*256 + t];
        float v[4][4];
        #pragma unroll
        for (int cc = 0; cc < 4; ++cc)
            #pragma unroll
            for (int r = 0; r < 4; ++r)
                v[cc][r] = frow[(size_t)cc*K_ + id4[r]];
        #pragma unroll
        for (int cc = 0; cc < 4; ++cc)
            #pragma unroll
            for (int r = 0; r < 4; ++r)
                grow[(size_t)cc*M_ + r*256 + t] = v[cc][r];
    } else {
        __shared__ float tile[32][33];
        int id = bid - 768;               // 0..1023
        int b = id >> 8, rem = id & 255;
        int m0 = (rem & 31) * 32, c0 = (rem >> 5) * 32;
        int tx = t & 31, ty = t >> 5;
        #pragma unroll
        for (int rr = 0; rr < 32; rr += 8)
            tile[ty+rr][tx] = sf[((size_t)b*256 + c0+ty+rr)*M_ + m0 + tx];
        __syncthreads();
        #pragma unroll
        for (int rr = 0; rr < 32; rr += 8)
            fused[((size_t)(b*M_ + m0+ty+rr))*512 + c0 + tx] = f2bf(tile[tx][ty+rr]);
    }
}

// ---------------------------------------------------------------------------
// fused LN: stats + apply + transpose -> xln bf16 [b][m][c]  (R8-verified)
__global__ __launch_bounds__(256) void k_ln_fused(const float* __restrict__ G,
                                                  const float* __restrict__ gamma,
                                                  const float* __restrict__ beta,
                                                  unsigned short* __restrict__ xln)
{
    int b = blockIdx.y, m0 = blockIdx.x * 32;
    int t = threadIdx.x;
    int ml = t & 31, cp = t >> 5;
    const float* Gb = G + (size_t)b * D_ * M_;
    float s = 0.f, q = 0.f;
    for (int c = cp; c < D_; c += 8) {
        float v = Gb[(size_t)c*M_ + m0 + ml];
        s += v; q += v*v;
    }
    __shared__ float sred[8][32], qred[8][32];
    __shared__ float mu[32], iv[32];
    sred[cp][ml] = s; qred[cp][ml] = q;
    __syncthreads();
    if (t < 32) {
        float S = 0.f, Q = 0.f;
        #pragma unroll
        for (int r = 0; r < 8; ++r) { S += sred[r][t]; Q += qred[r][t]; }
        float m_ = S * (1.f/768.f);
        mu[t] = m_;
        iv[t] = rsqrtf(Q * (1.f/768.f) - m_*m_ + 1e-5f);
    }
    __syncthreads();

    __shared__ float tile[64][33];
    int ty = t >> 5;
    int cx2 = t & 31;
    for (int c0 = 0; c0 < D_; c0 += 64) {
        __syncthreads();
        #pragma unroll
        for (int ri = 0; ri < 8; ++ri) {
            int cl = ty*8 + ri;
            tile[cl][ml] = Gb[(size_t)(c0+cl)*M_ + m0 + ml];
        }
        __syncthreads();
        float2 ga = *(const float2*)&gamma[c0 + 2*cx2];
        float2 be = *(const float2*)&beta[c0 + 2*cx2];
        #pragma unroll
        for (int ri = 0; ri < 4; ++ri) {
            int m_l = ty*4 + ri;
            float v0 = (tile[2*cx2+0][m_l] - mu[m_l]) * iv[m_l] * ga.x + be.x;
            float v1 = (tile[2*cx2+1][m_l] - mu[m_l]) * iv[m_l] * ga.y + be.y;
            ushort2 pk = make_ushort2(f2bf(v0), f2bf(v1));
            *(ushort2*)&xln[((size_t)((b<<10) + m0 + m_l))*D_ + c0 + 2*cx2] = pk;
        }
    }
}

// ---------------------------------------------------------------------------
// MFMA GEMM with double-buffered LDS (R8-verified)
__global__ __launch_bounds__(256) void k_gemm_mfma(
    const unsigned short* __restrict__ X, const unsigned short* __restrict__ W,
    const float* __restrict__ bias, int Kdim, int relu, int mode,
    unsigned short* __restrict__ Ybf, int rowStride, int colOff,
    float* __restrict__ Yf)
{
    __shared__ unsigned short Al[2][64*64];
    __shared__ unsigned short Wl[2][64*64];
    int t = threadIdx.x, l = t & 63, w = t >> 6;
    int m0 = blockIdx.x * 64, o0 = blockIdx.y * 64;
    f32x4 acc[4];
    #pragma unroll
    for (int j = 0; j < 4; ++j) acc[j] = (f32x4){0.f, 0.f, 0.f, 0.f};

    int lin0 = w*1024;
    int lb0  = lin0 + l*16;
    int row0 = lb0 >> 7;
    int ks0  = ((lb0 >> 4) & 7) ^ (row0 & 7);
    int lin1 = 4096 + w*1024;
    int lb1  = lin1 + l*16;
    int row1 = lb1 >> 7;
    int ks1  = ((lb1 >> 4) & 7) ^ (row1 & 7);

    int nt = Kdim >> 6;

    gload_lds16(X + (size_t)(m0+row0)*Kdim + ks0*8, (char*)&Al[0][0] + lin0);
    gload_lds16(W + (size_t)(o0+row0)*Kdim + ks0*8, (char*)&Wl[0][0] + lin0);
    gload_lds16(X + (size_t)(m0+row1)*Kdim + ks1*8, (char*)&Al[0][0] + lin1);
    gload_lds16(W + (size_t)(o0+row1)*Kdim + ks1*8, (char*)&Wl[0][0] + lin1);
    __syncthreads();

    for (int tt = 0; tt < nt; ++tt) {
        int cur = tt & 1;
        if (tt + 1 < nt) {
            int kc = (tt + 1) << 6;
            gload_lds16(X + (size_t)(m0+row0)*Kdim + kc + ks0*8, (char*)&Al[cur^1][0] + lin0);
            gload_lds16(W + (size_t)(o0+row0)*Kdim + kc + ks0*8, (char*)&Wl[cur^1][0] + lin0);
            gload_lds16(X + (size_t)(m0+row1)*Kdim + kc + ks1*8, (char*)&Al[cur^1][0] + lin1);
            gload_lds16(W + (size_t)(o0+row1)*Kdim + kc + ks1*8, (char*)&Wl[cur^1][0] + lin1);
        }
        #pragma unroll
        for (int kk = 0; kk < 2; ++kk) {
            int arow = w*16 + (l & 15);
            int h = l >> 4;
            bf16x8 a = *(const bf16x8*)&Al[cur][arow*64 + (((kk<<2)|h) ^ (arow & 7))*8];
            #pragma unroll
            for (int j = 0; j < 4; ++j) {
                int orow = j*16 + (l & 15);
                bf16x8 bfr = *(const bf16x8*)&Wl[cur][orow*64 + (((kk<<2)|h) ^ (orow & 7))*8];
                acc[j] = __builtin_amdgcn_mfma_f32_16x16x32_bf16(a, bfr, acc[j], 0, 0, 0);
            }
        }
        __syncthreads();
    }

    int mbase = m0 + w*16 + (l >> 4)*4;
    if (mode == 0) {
        #pragma unroll
        for (int j = 0; j < 4; ++j) {
            int o = o0 + j*16 + (l & 15);
            float bi = bias[o];
            #pragma unroll
            for (int r = 0; r < 4; ++r) {
                float v = acc[j][r] + bi;
                if (relu) v = fmaxf(v, 0.f);
                Ybf[(size_t)(mbase + r)*rowStride + colOff + o] = f2bf(v);
            }
        }
    } else {
        int b = mbase >> 10, ml = mbase & 1023;
        #pragma unroll
        for (int j = 0; j < 4; ++j) {
            int o = o0 + j*16 + (l & 15);
            float bi = bias[o];
            float4 sv = make_float4(acc[j][0]+bi, acc[j][1]+bi, acc[j][2]+bi, acc[j][3]+bi);
            *(float4*)&Yf[((size_t)(b*256 + o))*1024 + ml] = sv;
        }
    }
}

// ---------------------------------------------------------------------------
extern "C" void kernel_launch(void* const* d_in, const int* in_sizes, int n_in,
                              void* d_out, int out_size, void* d_ws, size_t ws_size,
                              hipStream_t stream)
{
    (void)in_sizes; (void)n_in; (void)out_size; (void)ws_size;
    const float* pc        = (const float*)d_in[0];
    const float* seed_xyz  = (const float*)d_in[1];
    const float* seed_feat = (const float*)d_in[2];
    const float* pts       = (const float*)d_in[3];
    const float* feat      = (const float*)d_in[4];
    const float* ln_g      = (const float*)d_in[5];
    const float* ln_b      = (const float*)d_in[6];
    const float* pw1       = (const float*)d_in[7];
    const float* pb1       = (const float*)d_in[8];
    const float* pw2       = (const float*)d_in[9];
    const float* pb2       = (const float*)d_in[10];
    const float* fw1       = (const float*)d_in[11];
    const float* fb1       = (const float*)d_in[12];
    const float* fw2       = (const float*)d_in[13];
    const float* fb2       = (const float*)d_in[14];
    float* out = (float*)d_out;

    char* ws = (char*)d_ws;
    float*          part  = (float*)(ws + OFF_PART);
    float*          rad   = (float*)(ws + OFF_RAD);
    int*            idx   = (int*)(ws + OFF_IDX);
    float4*         P4    = (float4*)(ws + OFF_P4);
    float2*         nnp   = (float2*)(ws + OFF_NNP);
    float*          G     = (float*)(ws + OFF_G);
    unsigned short* xln   = (unsigned short*)(ws + OFF_XLN);
    unsigned short* fused = (unsigned short*)(ws + OFF_FUSED);
    unsigned short* h2    = (unsigned short*)(ws + OFF_H2);
    unsigned short* Wb1   = (unsigned short*)(ws + OFF_WB1);
    unsigned short* Wcat  = (unsigned short*)(ws + OFF_WCAT);
    unsigned short* Wb4   = (unsigned short*)(ws + OFF_WB4);
    float*          bc    = (float*)(ws + OFF_BC);

    k_pre<<<832, 256, 0, stream>>>(pc, pw1, pw2, pb2, fw1, fb1, fw2,
                                   Wb1, Wcat, Wb4, bc, part);
    k_cs_rad<<<64, 256, 0, stream>>>(pc, part, rad);
    k_prep_pts<<<256, 256, 0, stream>>>(pts, part, rad, P4);
    k_nn_part<<<2048, 256, 0, stream>>>(seed_xyz, P4, part, rad, nnp);
    k_nn_reduce<<<16, 256, 0, stream>>>(nnp, idx);
    k_gather_tsf<<<1792, 256, 0, stream>>>(feat, idx, seed_feat, G, fused);
    k_ln_fused<<<dim3(M_/32, B_), 256, 0, stream>>>(G, ln_g, ln_b, xln);
    // gemm1: fused[:,256:512] = relu(pw1 @ xln + pb1)
    k_gemm_mfma<<<dim3(64, 4), 256, 0, stream>>>(xln, Wb1, pb1, 768, 1, 0, fused, 512, 256, nullptr);
    // gemm3': h2 = relu(Wcat @ fused + bc)
    k_gemm_mfma<<<dim3(64, 4), 256, 0, stream>>>(fused, Wcat, bc, 512, 1, 0, h2, 256, 0, nullptr);
    // gemm4: out = fw2 @ h2 + fb2 -> f32 [B][256][M]
    k_gemm_mfma<<<dim3(64, 4), 256, 0, stream>>>(h2, Wb4, fb2, 256, 0, 1, nullptr, 0, 0, out);
}

// Round 14
// 142.412 us; speedup vs baseline: 1.4158x; 1.0383x over previous
//
#include <hip/hip_runtime.h>
#include <math.h>

#define B_ 4
#define N_ 20000
#define M_ 1024
#define K_ 16384
#define D_ 768

typedef __attribute__((ext_vector_type(8))) short bf16x8;
typedef __attribute__((ext_vector_type(4))) float f32x4;

// Workspace offsets (ws is 768 MiB)
#define OFF_PART   0ul          // f32 [4][16][3] partial sums
#define OFF_RAD    1024ul       // f32 [4][16] partial max radius^2
#define OFF_IDX    4096ul       // int [4][1024]
#define OFF_P4     32768ul      // float4 [4][16384] normalized pts (1 MB)
#define OFF_NNP    1179648ul    // float2 [4][1024][4] NN partials (128 KB)
#define OFF_G      2097152ul    // f32 [4][768][1024]  (12.58 MB)
#define OFF_XLN    16777216ul   // bf16 [4096][768]
#define OFF_FUSED  25165824ul   // bf16 [4096][512]
#define OFF_H2     29360128ul   // bf16 [4096][256]
#define OFF_WB1    33554432ul   // bf16 [256][768]
#define OFF_WCAT   34603008ul   // bf16 [256][512]
#define OFF_WB4    35651584ul   // bf16 [256][256]
#define OFF_BC     36700160ul   // f32 [256]

__device__ inline unsigned short f2bf(float x) {
    union { float f; unsigned int u; } v; v.f = x;
    unsigned int r = v.u + 0x7fffu + ((v.u >> 16) & 1u);
    return (unsigned short)(r >> 16);
}

__device__ inline void gload_lds16(const void* g, void* lds) {
    __builtin_amdgcn_global_load_lds(
        (const __attribute__((address_space(1))) unsigned int*)g,
        (__attribute__((address_space(3))) unsigned int*)lds, 16, 0, 0);
}

__device__ inline void reduce_center(const float* part, int b,
                                     float& cx, float& cy, float& cz)
{
    cx = 0.f; cy = 0.f; cz = 0.f;
    #pragma unroll
    for (int r = 0; r < 16; ++r) {
        cx += part[(b*16+r)*3+0];
        cy += part[(b*16+r)*3+1];
        cz += part[(b*16+r)*3+2];
    }
    cx *= (1.f/N_); cy *= (1.f/N_); cz *= (1.f/N_);
}

__device__ inline float reduce_scale(const float* rad, int b)
{
    float m = 0.f;
    #pragma unroll
    for (int r = 0; r < 16; ++r) m = fmaxf(m, rad[b*16+r]);
    return fmaxf(sqrtf(m), 1e-6f);
}

// ---------------------------------------------------------------------------
// k_pre: weight cvt (bid<768) + Wcat-fold/bc (bid<256) + cs_sum (bid>=768)
__global__ __launch_bounds__(256) void k_pre(
    const float* __restrict__ pc,
    const float* __restrict__ pw1, const float* __restrict__ pw2,
    const float* __restrict__ pb2,
    const float* __restrict__ fw1, const float* __restrict__ fb1,
    const float* __restrict__ fw2,
    unsigned short* __restrict__ Wb1, unsigned short* __restrict__ Wcat,
    unsigned short* __restrict__ Wb4, float* __restrict__ bc,
    float* __restrict__ part)
{
    int bid = blockIdx.x, t = threadIdx.x;
    int lane = t & 63, wv = t >> 6;
    __shared__ float red[3][4];

    if (bid < 768) {
        int i0 = bid*256 + t;
        Wb1[i0] = f2bf(pw1[i0]);
        if (i0 < 65536) {
            int o = i0 >> 8, c = i0 & 255;
            Wcat[(size_t)o*512 + c] = f2bf(fw1[(size_t)o*512 + c]);
            Wb4[i0] = f2bf(fw2[i0]);
        }
    }
    if (bid < 256) {
        const float* fb = fw1 + (size_t)bid*512 + 256;
        float acc = 0.f;
        for (int j = 0; j < 256; ++j)
            acc = fmaf(fb[j], pw2[j*256 + t], acc);
        Wcat[(size_t)bid*512 + 256 + t] = f2bf(acc);
        float v = fb[t] * pb2[t];
        for (int off = 32; off; off >>= 1) v += __shfl_down(v, off, 64);
        if (!lane) red[0][wv] = v;
        __syncthreads();
        if (!t) bc[bid] = red[0][0]+red[0][1]+red[0][2]+red[0][3] + fb1[bid];
    } else if (bid >= 768) {
        int pi = bid - 768;
        int b = pi >> 4, chunk = pi & 15;
        const float* p = pc + (size_t)b * N_ * 3;
        int i0 = chunk * 1250;
        float sx = 0.f, sy = 0.f, sz = 0.f;
        for (int i = i0 + t; i < i0 + 1250; i += 256) {
            sx += p[i*3+0]; sy += p[i*3+1]; sz += p[i*3+2];
        }
        for (int off = 32; off; off >>= 1) {
            sx += __shfl_down(sx, off, 64);
            sy += __shfl_down(sy, off, 64);
            sz += __shfl_down(sz, off, 64);
        }
        if (!lane) { red[0][wv] = sx; red[1][wv] = sy; red[2][wv] = sz; }
        __syncthreads();
        if (!t) {
            part[(b*16+chunk)*3+0] = red[0][0]+red[0][1]+red[0][2]+red[0][3];
            part[(b*16+chunk)*3+1] = red[1][0]+red[1][1]+red[1][2]+red[1][3];
            part[(b*16+chunk)*3+2] = red[2][0]+red[2][1]+red[2][2]+red[2][3];
        }
    }
}

// ---------------------------------------------------------------------------
__global__ __launch_bounds__(256) void k_cs_rad(const float* __restrict__ pc,
                                                const float* __restrict__ part,
                                                float* __restrict__ rad)
{
    int blk = blockIdx.x, b = blk >> 4, pi = blk & 15;
    float cx, cy, cz;
    reduce_center(part, b, cx, cy, cz);
    const float* p = pc + (size_t)b * N_ * 3;
    int tid = threadIdx.x;
    int i0 = pi * 1250;
    float mx = 0.f;
    for (int i = i0 + tid; i < i0 + 1250; i += 256) {
        float dx = p[i*3+0]-cx, dy = p[i*3+1]-cy, dz = p[i*3+2]-cz;
        mx = fmaxf(mx, dx*dx + dy*dy + dz*dz);
    }
    for (int off = 32; off; off >>= 1) mx = fmaxf(mx, __shfl_down(mx, off, 64));
    __shared__ float red[4];
    int w = tid >> 6, l = tid & 63;
    if (!l) red[w] = mx;
    __syncthreads();
    if (!tid) rad[b*16+pi] = fmaxf(fmaxf(red[0], red[1]), fmaxf(red[2], red[3]));
}

// ---------------------------------------------------------------------------
// normalize pts -> float4(nx,ny,nz,|n|^2)
__global__ __launch_bounds__(256) void k_prep_pts(const float* __restrict__ pts,
                                                  const float* __restrict__ part,
                                                  const float* __restrict__ rad,
                                                  float4* __restrict__ P4)
{
    int blk = blockIdx.x, b = blk >> 6;
    float cx, cy, cz;
    reduce_center(part, b, cx, cy, cz);
    float sc = 1.f / reduce_scale(rad, b);
    int k = (blk & 63)*256 + threadIdx.x;
    const float* pp = pts + ((size_t)b*K_ + k)*3;
    float px = (pp[0]-cx)*sc, py = (pp[1]-cy)*sc, pz = (pp[2]-cz)*sc;
    P4[(size_t)b*K_ + k] = make_float4(px, py, pz, px*px + py*py + pz*pz);
}

// ---------------------------------------------------------------------------
// NN partial argmin: K split x4. Grid 2048 = [b:4][g:128][ks:4].
__global__ __launch_bounds__(256) void k_nn_part(const float* __restrict__ seed_xyz,
                                                 const float4* __restrict__ P4,
                                                 const float* __restrict__ part,
                                                 const float* __restrict__ rad,
                                                 float2* __restrict__ nnp)
{
    int blk = blockIdx.x;
    int ks = blk & 3, g = (blk >> 2) & 127, b = blk >> 9;
    float cx, cy, cz;
    reduce_center(part, b, cx, cy, cz);
    float scinv = 1.f / reduce_scale(rad, b);
    int t = threadIdx.x;
    int j = t & 31, s = t >> 5;
    int m = g*8 + s;
    const float* sp = seed_xyz + ((size_t)b*M_ + m)*3;
    float sx = (sp[0]-cx)*scinv, sy = (sp[1]-cy)*scinv, sz = (sp[2]-cz)*scinv;
    float ssq = sx*sx + sy*sy + sz*sz;
    const float4* Pb = P4 + (size_t)b*K_ + ks*4096;

    float best[4] = {3.4e38f, 3.4e38f, 3.4e38f, 3.4e38f};
    int   bk[4]   = {0, 0, 0, 0};
    for (int i = 0; i < 128; i += 4) {
        #pragma unroll
        for (int r = 0; r < 4; ++r) {
            int kk = (i + r)*32 + j;
            float4 q = Pb[kk];
            float d2 = ssq + q.w - 2.f*(sx*q.x + sy*q.y + sz*q.z);
            if (d2 < best[r]) { best[r] = d2; bk[r] = kk; }
        }
    }
    float bm = best[0]; int bmk = bk[0];
    #pragma unroll
    for (int r = 1; r < 4; ++r)
        if (best[r] < bm || (best[r] == bm && bk[r] < bmk)) { bm = best[r]; bmk = bk[r]; }
    #pragma unroll
    for (int mask = 16; mask; mask >>= 1) {
        float ob = __shfl_xor(bm, mask, 64);
        int   ok = __shfl_xor(bmk, mask, 64);
        if (ob < bm || (ob == bm && ok < bmk)) { bm = ob; bmk = ok; }
    }
    if (j == 0)
        nnp[((size_t)(b*M_ + m) << 2) + ks] = make_float2(bm, __int_as_float(ks*4096 + bmk));
}

// Final merge over the 4 K-chunks (in order -> ties pick lower chunk = lower k)
__global__ __launch_bounds__(256) void k_nn_reduce(const float2* __restrict__ nnp,
                                                   int* __restrict__ idx)
{
    int i = blockIdx.x*256 + threadIdx.x;
    float bm = 3.4e38f; int bmk = 0;
    bool first = true;
    #pragma unroll
    for (int r = 0; r < 4; ++r) {
        float2 v = nnp[((size_t)i << 2) + r];
        int k = __float_as_int(v.y);
        if (first || v.x < bm || (v.x == bm && k < bmk)) { bm = v.x; bmk = k; first = false; }
    }
    idx[i] = bmk;
}

// ---------------------------------------------------------------------------
// gather: bid<1536 -> TWO channel rows per block (8 scattered loads in flight);
// bid>=1536 -> seed-feature transpose tiles
__global__ __launch_bounds__(256) void k_gather_tsf(const float* __restrict__ feat,
                                                    const int* __restrict__ idx,
                                                    const float* __restrict__ sf,
                                                    float* __restrict__ G,
                                                    unsigned short* __restrict__ fused)
{
    int bid = blockIdx.x, t = threadIdx.x;
    if (bid < 1536) {
        int b = bid / 384;
        int c = (bid - b*384) * 2;
        const float* frow0 = feat + ((size_t)b*D_ + c) * K_;
        const float* frow1 = frow0 + K_;
        const int* ib = idx + b*M_;
        float* g0 = G + ((size_t)b*D_ + c) * M_;
        float* g1 = g0 + M_;
        int id4[4];
        #pragma unroll
        for (int r = 0; r < 4; ++r) id4[r] = ib[r*256 + t];
        float v0[4], v1[4];
        #pragma unroll
        for (int r = 0; r < 4; ++r) v0[r] = frow0[id4[r]];
        #pragma unroll
        for (int r = 0; r < 4; ++r) v1[r] = frow1[id4[r]];
        #pragma unroll
        for (int r = 0; r < 4; ++r) g0[r*256 + t] = v0[r];
        #pragma unroll
        for (int r = 0; r < 4; ++r) g1[r*256 + t] = v1[r];
    } else {
        __shared__ float tile[32][33];
        int id = bid - 1536;               // 0..1023
        int b = id >> 8, rem = id & 255;
        int m0 = (rem & 31) * 32, c0 = (rem >> 5) * 32;
        int tx = t & 31, ty = t >> 5;
        #pragma unroll
        for (int rr = 0; rr < 32; rr += 8)
            tile[ty+rr][tx] = sf[((size_t)b*256 + c0+ty+rr)*M_ + m0 + tx];
        __syncthreads();
        #pragma unroll
        for (int rr = 0; rr < 32; rr += 8)
            fused[((size_t)(b*M_ + m0+ty+rr))*512 + c0 + tx] = f2bf(tile[tx][ty+rr]);
    }
}

// ---------------------------------------------------------------------------
// fused LN: stats + apply + transpose -> xln bf16 [b][m][c]
__global__ __launch_bounds__(256) void k_ln_fused(const float* __restrict__ G,
                                                  const float* __restrict__ gamma,
                                                  const float* __restrict__ beta,
                                                  unsigned short* __restrict__ xln)
{
    int b = blockIdx.y, m0 = blockIdx.x * 32;
    int t = threadIdx.x;
    int ml = t & 31, cp = t >> 5;
    const float* Gb = G + (size_t)b * D_ * M_;
    float s = 0.f, q = 0.f;
    for (int c = cp; c < D_; c += 8) {
        float v = Gb[(size_t)c*M_ + m0 + ml];
        s += v; q += v*v;
    }
    __shared__ float sred[8][32], qred[8][32];
    __shared__ float mu[32], iv[32];
    sred[cp][ml] = s; qred[cp][ml] = q;
    __syncthreads();
    if (t < 32) {
        float S = 0.f, Q = 0.f;
        #pragma unroll
        for (int r = 0; r < 8; ++r) { S += sred[r][t]; Q += qred[r][t]; }
        float m_ = S * (1.f/768.f);
        mu[t] = m_;
        iv[t] = rsqrtf(Q * (1.f/768.f) - m_*m_ + 1e-5f);
    }
    __syncthreads();

    __shared__ float tile[64][33];
    int ty = t >> 5;
    int cx2 = t & 31;
    for (int c0 = 0; c0 < D_; c0 += 64) {
        __syncthreads();
        #pragma unroll
        for (int ri = 0; ri < 8; ++ri) {
            int cl = ty*8 + ri;
            tile[cl][ml] = Gb[(size_t)(c0+cl)*M_ + m0 + ml];
        }
        __syncthreads();
        float2 ga = *(const float2*)&gamma[c0 + 2*cx2];
        float2 be = *(const float2*)&beta[c0 + 2*cx2];
        #pragma unroll
        for (int ri = 0; ri < 4; ++ri) {
            int m_l = ty*4 + ri;
            float v0 = (tile[2*cx2+0][m_l] - mu[m_l]) * iv[m_l] * ga.x + be.x;
            float v1 = (tile[2*cx2+1][m_l] - mu[m_l]) * iv[m_l] * ga.y + be.y;
            ushort2 pk = make_ushort2(f2bf(v0), f2bf(v1));
            *(ushort2*)&xln[((size_t)((b<<10) + m0 + m_l))*D_ + c0 + 2*cx2] = pk;
        }
    }
}

// ---------------------------------------------------------------------------
// MFMA GEMM with double-buffered LDS (R8-verified)
__global__ __launch_bounds__(256) void k_gemm_mfma(
    const unsigned short* __restrict__ X, const unsigned short* __restrict__ W,
    const float* __restrict__ bias, int Kdim, int relu, int mode,
    unsigned short* __restrict__ Ybf, int rowStride, int colOff,
    float* __restrict__ Yf)
{
    __shared__ unsigned short Al[2][64*64];
    __shared__ unsigned short Wl[2][64*64];
    int t = threadIdx.x, l = t & 63, w = t >> 6;
    int m0 = blockIdx.x * 64, o0 = blockIdx.y * 64;
    f32x4 acc[4];
    #pragma unroll
    for (int j = 0; j < 4; ++j) acc[j] = (f32x4){0.f, 0.f, 0.f, 0.f};

    int lin0 = w*1024;
    int lb0  = lin0 + l*16;
    int row0 = lb0 >> 7;
    int ks0  = ((lb0 >> 4) & 7) ^ (row0 & 7);
    int lin1 = 4096 + w*1024;
    int lb1  = lin1 + l*16;
    int row1 = lb1 >> 7;
    int ks1  = ((lb1 >> 4) & 7) ^ (row1 & 7);

    int nt = Kdim >> 6;

    gload_lds16(X + (size_t)(m0+row0)*Kdim + ks0*8, (char*)&Al[0][0] + lin0);
    gload_lds16(W + (size_t)(o0+row0)*Kdim + ks0*8, (char*)&Wl[0][0] + lin0);
    gload_lds16(X + (size_t)(m0+row1)*Kdim + ks1*8, (char*)&Al[0][0] + lin1);
    gload_lds16(W + (size_t)(o0+row1)*Kdim + ks1*8, (char*)&Wl[0][0] + lin1);
    __syncthreads();

    for (int tt = 0; tt < nt; ++tt) {
        int cur = tt & 1;
        if (tt + 1 < nt) {
            int kc = (tt + 1) << 6;
            gload_lds16(X + (size_t)(m0+row0)*Kdim + kc + ks0*8, (char*)&Al[cur^1][0] + lin0);
            gload_lds16(W + (size_t)(o0+row0)*Kdim + kc + ks0*8, (char*)&Wl[cur^1][0] + lin0);
            gload_lds16(X + (size_t)(m0+row1)*Kdim + kc + ks1*8, (char*)&Al[cur^1][0] + lin1);
            gload_lds16(W + (size_t)(o0+row1)*Kdim + kc + ks1*8, (char*)&Wl[cur^1][0] + lin1);
        }
        #pragma unroll
        for (int kk = 0; kk < 2; ++kk) {
            int arow = w*16 + (l & 15);
            int h = l >> 4;
            bf16x8 a = *(const bf16x8*)&Al[cur][arow*64 + (((kk<<2)|h) ^ (arow & 7))*8];
            #pragma unroll
            for (int j = 0; j < 4; ++j) {
                int orow = j*16 + (l & 15);
                bf16x8 bfr = *(const bf16x8*)&Wl[cur][orow*64 + (((kk<<2)|h) ^ (orow & 7))*8];
                acc[j] = __builtin_amdgcn_mfma_f32_16x16x32_bf16(a, bfr, acc[j], 0, 0, 0);
            }
        }
        __syncthreads();
    }

    int mbase = m0 + w*16 + (l >> 4)*4;
    if (mode == 0) {
        #pragma unroll
        for (int j = 0; j < 4; ++j) {
            int o = o0 + j*16 + (l & 15);
            float bi = bias[o];
            #pragma unroll
            for (int r = 0; r < 4; ++r) {
                float v = acc[j][r] + bi;
                if (relu) v = fmaxf(v, 0.f);
                Ybf[(size_t)(mbase + r)*rowStride + colOff + o] = f2bf(v);
            }
        }
    } else {
        int b = mbase >> 10, ml = mbase & 1023;
        #pragma unroll
        for (int j = 0; j < 4; ++j) {
            int o = o0 + j*16 + (l & 15);
            float bi = bias[o];
            float4 sv = make_float4(acc[j][0]+bi, acc[j][1]+bi, acc[j][2]+bi, acc[j][3]+bi);
            *(float4*)&Yf[((size_t)(b*256 + o))*1024 + ml] = sv;
        }
    }
}

// ---------------------------------------------------------------------------
extern "C" void kernel_launch(void* const* d_in, const int* in_sizes, int n_in,
                              void* d_out, int out_size, void* d_ws, size_t ws_size,
                              hipStream_t stream)
{
    (void)in_sizes; (void)n_in; (void)out_size; (void)ws_size;
    const float* pc        = (const float*)d_in[0];
    const float* seed_xyz  = (const float*)d_in[1];
    const float* seed_feat = (const float*)d_in[2];
    const float* pts       = (const float*)d_in[3];
    const float* feat      = (const float*)d_in[4];
    const float* ln_g      = (const float*)d_in[5];
    const float* ln_b      = (const float*)d_in[6];
    const float* pw1       = (const float*)d_in[7];
    const float* pb1       = (const float*)d_in[8];
    const float* pw2       = (const float*)d_in[9];
    const float* pb2       = (const float*)d_in[10];
    const float* fw1       = (const float*)d_in[11];
    const float* fb1       = (const float*)d_in[12];
    const float* fw2       = (const float*)d_in[13];
    const float* fb2       = (const float*)d_in[14];
    float* out = (float*)d_out;

    char* ws = (char*)d_ws;
    float*          part  = (float*)(ws + OFF_PART);
    float*          rad   = (float*)(ws + OFF_RAD);
    int*            idx   = (int*)(ws + OFF_IDX);
    float4*         P4    = (float4*)(ws + OFF_P4);
    float2*         nnp   = (float2*)(ws + OFF_NNP);
    float*          G     = (float*)(ws + OFF_G);
    unsigned short* xln   = (unsigned short*)(ws + OFF_XLN);
    unsigned short* fused = (unsigned short*)(ws + OFF_FUSED);
    unsigned short* h2    = (unsigned short*)(ws + OFF_H2);
    unsigned short* Wb1   = (unsigned short*)(ws + OFF_WB1);
    unsigned short* Wcat  = (unsigned short*)(ws + OFF_WCAT);
    unsigned short* Wb4   = (unsigned short*)(ws + OFF_WB4);
    float*          bc    = (float*)(ws + OFF_BC);

    k_pre<<<832, 256, 0, stream>>>(pc, pw1, pw2, pb2, fw1, fb1, fw2,
                                   Wb1, Wcat, Wb4, bc, part);
    k_cs_rad<<<64, 256, 0, stream>>>(pc, part, rad);
    k_prep_pts<<<256, 256, 0, stream>>>(pts, part, rad, P4);
    k_nn_part<<<2048, 256, 0, stream>>>(seed_xyz, P4, part, rad, nnp);
    k_nn_reduce<<<16, 256, 0, stream>>>(nnp, idx);
    k_gather_tsf<<<2560, 256, 0, stream>>>(feat, idx, seed_feat, G, fused);
    k_ln_fused<<<dim3(M_/32, B_), 256, 0, stream>>>(G, ln_g, ln_b, xln);
    // gemm1: fused[:,256:512] = relu(pw1 @ xln + pb1)
    k_gemm_mfma<<<dim3(64, 4), 256, 0, stream>>>(xln, Wb1, pb1, 768, 1, 0, fused, 512, 256, nullptr);
    // gemm3': h2 = relu(Wcat @ fused + bc)
    k_gemm_mfma<<<dim3(64, 4), 256, 0, stream>>>(fused, Wcat, bc, 512, 1, 0, h2, 256, 0, nullptr);
    // gemm4: out = fw2 @ h2 + fb2 -> f32 [B][256][M]
    k_gemm_mfma<<<dim3(64, 4), 256, 0, stream>>>(h2, Wb4, fb2, 256, 0, 1, nullptr, 0, 0, out);
}